// Round 8
// baseline (419.434 us; speedup 1.0000x reference)
//
#include <hip/hip_runtime.h>
#include <cstddef>

// HVAE tree decoder, fused single kernel, register-resident weights.
// Block = 512 thr (8 waves) = 32 batch rows; wave w owns the 16-col nt-slice w
// of every N=128 matmul. Each wave's weight fragments (gru_a 15, gru_f 15,
// u 8 = 38 frags = 152 VGPRs) are loaded ONCE before the 31-node loop --
// eliminates the per-node L2 weight re-fetch that bounded round 7.
// h/probs stacks in LDS; pred staged in LDS and dumped as full-line
// nontemporal float4. Grid = B/32 = 512, 1 block/CU, 8 waves/CU.

#define BB   16384
#define HH   128
#define OO   32

typedef __attribute__((ext_vector_type(8))) short bf8;
typedef __attribute__((ext_vector_type(4))) float f4;

#define MFMA(a, b, c) __builtin_amdgcn_mfma_f32_16x16x32_bf16(a, b, c, 0, 0, 0)

// packed-weight offsets in ws (shorts)
#define PW_Z2H 0         // [64x128]  -> 8192
#define PW_AWI 8192      // [96x128]  -> 12288
#define PW_AWH 20480     // [384x128] -> 49152
#define PW_FWI 69632     // [96x128]  -> 12288
#define PW_FWH 81920     // [384x128] -> 49152
#define PW_UA  131072    // [128x128] -> 16384
#define PW_UF  147456    // [128x128] -> 16384
#define PW_H2O 163840    // [128x32]  -> 4096
#define PW_END 167936

#define SH   136   // LDS h row stride (shorts)
#define PSLD 40    // LDS probs row stride (shorts)
#define SZ   72    // LDS z-staging row stride (shorts), 16B-aligned, depads banks

__device__ __forceinline__ short f2bf(float f) {
  union { float f; unsigned u; } v; v.f = f;
  unsigned r = v.u + 0x7fff + ((v.u >> 16) & 1);   // RNE
  return (short)(r >> 16);
}
__device__ __forceinline__ float bf2f(short h) {
  union { unsigned u; float f; } v;
  v.u = ((unsigned)(unsigned short)h) << 16;
  return v.f;
}
__device__ __forceinline__ float sigmoidf_(float x) { return 1.0f / (1.0f + __expf(-x)); }
__device__ __forceinline__ float tanhf_(float x) {
  float ax = fabsf(x), e = __expf(-2.0f * ax), t = (1.0f - e) / (1.0f + e);
  return x >= 0.0f ? t : -t;
}

// ---------------- repack: fp32 [K][N] -> B-frag-major bf16 -------------------
// P[((nt*KC + kc)*64 + lane)*8 + j] = W[kc*32 + (lane>>4)*8 + j][nt*16 + (lane&15)]
template <int K, int N>
__device__ __forceinline__ void repack_one(const float* __restrict__ W,
                                           short* __restrict__ P, int idx) {
  const int KC = K / 32;
  const int j = idx & 7, lane = (idx >> 3) & 63, rest = idx >> 9;
  const int kc = rest % KC, nt = rest / KC;
  const int k = kc * 32 + ((lane >> 4) << 3) + j;
  const int n = nt * 16 + (lane & 15);
  P[idx] = f2bf(W[(size_t)k * N + n]);
}

__global__ __launch_bounds__(256) void k_repack(
    const float* __restrict__ z2hw, const float* __restrict__ awi,
    const float* __restrict__ awh, const float* __restrict__ fwi,
    const float* __restrict__ fwh, const float* __restrict__ uaw,
    const float* __restrict__ ufw, const float* __restrict__ h2ow,
    short* __restrict__ ws) {
  const int t = blockIdx.x * 256 + threadIdx.x;
  if (t < PW_AWI)        repack_one<64, 128>(z2hw, ws + PW_Z2H, t - PW_Z2H);
  else if (t < PW_AWH)   repack_one<96, 128>(awi, ws + PW_AWI, t - PW_AWI);
  else if (t < PW_FWI)   repack_one<384, 128>(awh, ws + PW_AWH, t - PW_AWH);
  else if (t < PW_FWH)   repack_one<96, 128>(fwi, ws + PW_FWI, t - PW_FWI);
  else if (t < PW_UA)    repack_one<384, 128>(fwh, ws + PW_FWH, t - PW_FWH);
  else if (t < PW_UF)    repack_one<128, 128>(uaw, ws + PW_UA, t - PW_UA);
  else if (t < PW_H2O)   repack_one<128, 128>(ufw, ws + PW_UF, t - PW_UF);
  else if (t < PW_END)   repack_one<128, 32>(h2ow, ws + PW_H2O, t - PW_H2O);
}

__device__ __forceinline__ bf8 ldfrag(const short* __restrict__ p, int f, int lane) {
  return *(const bf8*)(p + ((size_t)(f * 64 + lane)) * 8);
}

// GRU for wave's nt-slice (16 cols), both 16-row tiles, rt-sequential.
// x from LDS probs block (stride PSLD), h from LDS h block (stride SH).
// WI[3] (gate frags), WH[12] (gate*4+c frags) live in the caller's registers.
__device__ __forceinline__ void gru1(const short* xs, const short* hsrc,
                                     const bf8* WI, const bf8* WH,
                                     float b_r, float b_z, float b_n, float b_h2,
                                     int l15, int q, int cw, f4* hv) {
#pragma unroll
  for (int rt = 0; rt < 2; ++rt) {
    const bf8 ax = *(const bf8*)(xs + (rt * 16 + l15) * PSLD + q * 8);
    bf8 ah[4];
#pragma unroll
    for (int c = 0; c < 4; ++c)
      ah[c] = *(const bf8*)(hsrc + (rt * 16 + l15) * SH + c * 32 + q * 8);
    f4 t2 = (f4){b_h2, b_h2, b_h2, b_h2};    // h@wh2 + bh2
    f4 r  = (f4){b_r, b_r, b_r, b_r};
    f4 zz = (f4){b_z, b_z, b_z, b_z};
#pragma unroll
    for (int c = 0; c < 4; ++c) t2 = MFMA(ah[c], WH[8 + c], t2);
    r = MFMA(ax, WI[0], r);
#pragma unroll
    for (int c = 0; c < 4; ++c) r = MFMA(ah[c], WH[c], r);
    zz = MFMA(ax, WI[1], zz);
#pragma unroll
    for (int c = 0; c < 4; ++c) zz = MFMA(ah[c], WH[4 + c], zz);
#pragma unroll
    for (int j = 0; j < 4; ++j) t2[j] = t2[j] * sigmoidf_(r[j]) + b_n;
    t2 = MFMA(ax, WI[2], t2);                // n preact complete
#pragma unroll
    for (int j = 0; j < 4; ++j) {
      const float hc = bf2f(hsrc[(rt * 16 + q * 4 + j) * SH + cw]);
      const float z = sigmoidf_(zz[j]);
      const float n = tanhf_(t2[j]);
      hv[rt][j] = (1.0f - z) * n + z * hc;
    }
  }
}

// preorder schedule, depth 4: type 0=root, 1=left child (gru_a), 2=right child
__device__ const unsigned char d_TYPE[31] =
    {0,1,1,1,1,2,2,1,2,2,1,1,2,2,1,2,2,1,1,1,2,2,1,2,2,1,1,2,2,1,2};
__device__ const unsigned char d_LVL[31] =
    {0,1,2,3,4,4,3,4,4,2,3,4,4,3,4,4,1,2,3,4,4,3,4,4,2,3,4,4,3,4,4};

// ---------------- the fused tree kernel -------------------------------------
__global__ __launch_bounds__(512, 2) void k_tree(
    const float* __restrict__ z, const short* __restrict__ pw,
    const float* __restrict__ z2hb, const float* __restrict__ abi,
    const float* __restrict__ abh, const float* __restrict__ fbi,
    const float* __restrict__ fbh, const float* __restrict__ uab,
    const float* __restrict__ ufb, const float* __restrict__ h2ob,
    float* __restrict__ out) {
  __shared__ __align__(16) short hstk[5 * 32 * SH];   // 43520 B
  __shared__ __align__(16) short hfb[32 * SH];        // 8704 B (overlays: z stage, spred)
  __shared__ __align__(16) short pstk[5 * 32 * PSLD]; // 12800 B => 65024 B total
  float* spred = (float*)hfb;
  short* zb = hfb;
  const int tid = threadIdx.x;
  const int lane = tid & 63, w = tid >> 6;            // w = this wave's nt-slice
  const int l15 = lane & 15, q = lane >> 4;
  const int cw = w * 16 + l15;                        // this lane's output column
  const int r0 = blockIdx.x * 32;

  // ---- persistent per-wave weight fragments (loaded once, reused 31 nodes) --
  bf8 AWI[3], AWH[12], FWI[3], FWH[12], UF[4], UA[4];
#pragma unroll
  for (int g = 0; g < 3; ++g) {
    AWI[g] = ldfrag(pw + PW_AWI, w * 3 + g, lane);
    FWI[g] = ldfrag(pw + PW_FWI, w * 3 + g, lane);
  }
#pragma unroll
  for (int f = 0; f < 12; ++f) {
    AWH[f] = ldfrag(pw + PW_AWH, w * 12 + f, lane);
    FWH[f] = ldfrag(pw + PW_FWH, w * 12 + f, lane);
  }
#pragma unroll
  for (int c = 0; c < 4; ++c) {
    UF[c] = ldfrag(pw + PW_UF, w * 4 + c, lane);
    UA[c] = ldfrag(pw + PW_UA, w * 4 + c, lane);
  }
  // ---- persistent biases ----------------------------------------------------
  const float ba_r  = abi[cw] + abh[cw];
  const float ba_z  = abi[HH + cw] + abh[HH + cw];
  const float ba_n  = abi[2 * HH + cw];
  const float ba_h2 = abh[2 * HH + cw];
  const float bf_r  = fbi[cw] + fbh[cw];
  const float bf_z  = fbi[HH + cw] + fbh[HH + cw];
  const float bf_n  = fbi[2 * HH + cw];
  const float bf_h2 = fbh[2 * HH + cw];
  const float bu    = ufb[cw] + uab[cw];
  const float bp0   = h2ob[l15], bp1 = h2ob[16 + l15];

  // ---- root: h_in[0] = z @ z2h + b (z converted in-block via LDS) -----------
  {
    const f4 v = *(const f4*)(z + (size_t)r0 * 64 + tid * 4);
    const int zr = tid >> 4, zc = (tid & 15) * 4;
#pragma unroll
    for (int k = 0; k < 4; ++k) zb[zr * SZ + zc + k] = f2bf(v[k]);
    __syncthreads();
    const bf8 W0 = ldfrag(pw + PW_Z2H, w * 2 + 0, lane);
    const bf8 W1 = ldfrag(pw + PW_Z2H, w * 2 + 1, lane);
    const float bz = z2hb[cw];
    f4 hv[2];
#pragma unroll
    for (int rt = 0; rt < 2; ++rt) {
      const bf8 a0 = *(const bf8*)(zb + (rt * 16 + l15) * SZ + q * 8);
      const bf8 a1 = *(const bf8*)(zb + (rt * 16 + l15) * SZ + 32 + q * 8);
      f4 acc = (f4){bz, bz, bz, bz};
      acc = MFMA(a0, W0, acc);
      acc = MFMA(a1, W1, acc);
      hv[rt] = acc;
    }
#pragma unroll
    for (int rt = 0; rt < 2; ++rt)
#pragma unroll
      for (int j = 0; j < 4; ++j)
        hstk[(rt * 16 + q * 4 + j) * SH + cw] = f2bf(hv[rt][j]);
  }
  __syncthreads();

#pragma unroll 1
  for (int i = 0; i < 31; ++i) {
    const int t = d_TYPE[i];
    const int L = d_LVL[i];
    short* hcur = hstk + L * 32 * SH;
    short* pcur = pstk + L * 32 * PSLD;

    if (t == 2) {
      // h_f = gru_f(probs_sib, h_sib)
      f4 hf[2];
      gru1(pcur, hcur, FWI, FWH, bf_r, bf_z, bf_n, bf_h2, l15, q, cw, hf);
#pragma unroll
      for (int rt = 0; rt < 2; ++rt)
#pragma unroll
        for (int j = 0; j < 4; ++j)
          hfb[(rt * 16 + q * 4 + j) * SH + cw] = f2bf(hf[rt][j]);
      __syncthreads();
      // h2 = tanh(h_f@uf + h_par@ua + b)
      const short* hpar = hstk + (L - 1) * 32 * SH;
      f4 uv[2];
#pragma unroll
      for (int rt = 0; rt < 2; ++rt) {
        bf8 af[4], ap[4];
#pragma unroll
        for (int c = 0; c < 4; ++c) {
          af[c] = *(const bf8*)(hfb + (rt * 16 + l15) * SH + c * 32 + q * 8);
          ap[c] = *(const bf8*)(hpar + (rt * 16 + l15) * SH + c * 32 + q * 8);
        }
        f4 acc = (f4){bu, bu, bu, bu};
#pragma unroll
        for (int c = 0; c < 4; ++c) {
          acc = MFMA(af[c], UF[c], acc);
          acc = MFMA(ap[c], UA[c], acc);
        }
#pragma unroll
        for (int j = 0; j < 4; ++j) acc[j] = tanhf_(acc[j]);
        uv[rt] = acc;
      }
#pragma unroll
      for (int rt = 0; rt < 2; ++rt)
#pragma unroll
        for (int j = 0; j < 4; ++j)
          hcur[(rt * 16 + q * 4 + j) * SH + cw] = f2bf(uv[rt][j]);
      __syncthreads();
    }

    // pred + softmax: waves 0,1 each handle one 16-row tile, full N=32
    if (w < 2) {
      bf8 a[4];
#pragma unroll
      for (int c = 0; c < 4; ++c)
        a[c] = *(const bf8*)(hcur + (w * 16 + l15) * SH + c * 32 + q * 8);
      f4 p0 = (f4){bp0, bp0, bp0, bp0};
      f4 p1 = (f4){bp1, bp1, bp1, bp1};
#pragma unroll
      for (int c = 0; c < 4; ++c) {
        p0 = MFMA(a[c], ldfrag(pw + PW_H2O, c, lane), p0);
        p1 = MFMA(a[c], ldfrag(pw + PW_H2O, 4 + c, lane), p1);
      }
#pragma unroll
      for (int j = 0; j < 4; ++j) {
        const float v0 = p0[j], v1 = p1[j];
        float mx = fmaxf(v0, v1);
#pragma unroll
        for (int s = 1; s < 16; s <<= 1) mx = fmaxf(mx, __shfl_xor(mx, s));
        const float e0 = __expf(v0 - mx), e1 = __expf(v1 - mx);
        float ss = e0 + e1;
#pragma unroll
        for (int s = 1; s < 16; s <<= 1) ss += __shfl_xor(ss, s);
        const float inv = 1.0f / ss;
        const int row = w * 16 + q * 4 + j;
        spred[row * 32 + l15] = v0;
        spred[row * 32 + 16 + l15] = v1;
        pcur[row * PSLD + l15] = f2bf(e0 * inv);
        pcur[row * PSLD + 16 + l15] = f2bf(e1 * inv);
      }
    }
    __syncthreads();

    // dump pred: 32 rows x 32 cols fp32 = 4KB contiguous, nontemporal
    if (tid < 256) {
      const f4 v = *(const f4*)(spred + tid * 4);
      __builtin_nontemporal_store(
          v, (f4*)(out + (size_t)i * BB * OO + (size_t)r0 * OO) + tid);
    }

    // non-leaf: h_in[L+1] = gru_a(probs, h_in[L])
    if (L < 4) {
      f4 hv[2];
      gru1(pcur, hcur, AWI, AWH, ba_r, ba_z, ba_n, ba_h2, l15, q, cw, hv);
#pragma unroll
      for (int rt = 0; rt < 2; ++rt)
#pragma unroll
        for (int j = 0; j < 4; ++j)
          hstk[(L + 1) * 32 * SH + (rt * 16 + q * 4 + j) * SH + cw] =
              f2bf(hv[rt][j]);
    }
    // barrier protects spred/hfb reuse and hstk[L+1] for the next node
    __syncthreads();
  }
}

// ---------------- host ------------------------------------------------------
extern "C" void kernel_launch(void* const* d_in, const int* in_sizes, int n_in,
                              void* d_out, int out_size, void* d_ws, size_t ws_size,
                              hipStream_t stream) {
  const float* z    = (const float*)d_in[0];
  const float* z2hw = (const float*)d_in[1];
  const float* z2hb = (const float*)d_in[2];
  const float* h2ow = (const float*)d_in[3];
  const float* h2ob = (const float*)d_in[4];
  const float* awi  = (const float*)d_in[5];
  const float* abi  = (const float*)d_in[6];
  const float* awh  = (const float*)d_in[7];
  const float* abh  = (const float*)d_in[8];
  const float* fwi  = (const float*)d_in[9];
  const float* fbi  = (const float*)d_in[10];
  const float* fwh  = (const float*)d_in[11];
  const float* fbh  = (const float*)d_in[12];
  const float* uaw  = (const float*)d_in[13];
  const float* uab  = (const float*)d_in[14];
  const float* ufw  = (const float*)d_in[15];
  const float* ufb  = (const float*)d_in[16];

  float* out = (float*)d_out;
  short* ws  = (short*)d_ws;

  k_repack<<<(PW_END + 255) / 256, 256, 0, stream>>>(
      z2hw, awi, awh, fwi, fwh, uaw, ufw, h2ow, ws);

  k_tree<<<BB / 32, 512, 0, stream>>>(
      z, ws, z2hb, abi, abh, fbi, fbh, uab, ufb, h2ob, out);
}